// Round 14
// baseline (450.556 us; speedup 1.0000x reference)
//
#include <hip/hip_runtime.h>
#include <hip/hip_cooperative_groups.h>
#include <math.h>

namespace cg = cooperative_groups;

// Problem constants
#define B_  8
#define S_  384
#define H_  12
#define HD_ 64
#define E_  768
#define D_  768

typedef float  floatx4 __attribute__((ext_vector_type(4)));
typedef __bf16 bf16x8  __attribute__((ext_vector_type(8)));
typedef unsigned int ux4 __attribute__((ext_vector_type(4)));

__device__ __forceinline__ unsigned short f2bf(float f) {
    union { float f; unsigned u; } x; x.f = f;
    unsigned r = x.u + 0x7fff + ((x.u >> 16) & 1);
    return (unsigned short)(r >> 16);
}
__device__ __forceinline__ float bf2f(unsigned short u) {
    union { unsigned u; float f; } x; x.u = ((unsigned)u) << 16;
    return x.f;
}
__device__ __forceinline__ bf16x8 gld8(const unsigned short* p) {
    return __builtin_bit_cast(bf16x8, *(const ux4*)p);
}
__device__ __forceinline__ int tadr(int row, int cD) {
    return (row * 8 + (cD ^ (row & 7))) * 8;
}
__device__ __forceinline__ bf16x8 lds8(const unsigned short* base, int row, int cD) {
    return __builtin_bit_cast(bf16x8, *(const ux4*)(base + tadr(row, cD)));
}

struct KArgs {
    const float *x, *sep;
    const int *mask, *seg;
    const float *Wq,*bq,*Wk,*bk,*Wv,*bv,*rel128,*Wpk,*bpk,*Wpq,*bpq;
    const float *same_bias,*cross_bias,*sep_scale,*sep_decay,*Wo,*bo;
    unsigned short *xb;      // contiguous: xb | wq wk wv wo wpk wpq | relb
    unsigned short *relb;
    unsigned short *qb,*kb,*vtb,*pkb,*pqb,*valsb,*partO;
    float *partml, *out;
    int nblk;
};

// ---------------------------------------------------------------------------
// Convert body: element-group i (of 1622016 float4 groups) fp32 -> bf16.
// ---------------------------------------------------------------------------
__device__ __forceinline__ void convert_elem(const KArgs& a, int i)
{
    const float* srcW[7] = { a.Wq, a.Wk, a.Wv, a.Wo, a.Wpk, a.Wpq, a.rel128 };
    const int e = i * 4;
    const int sg = e / 589824;
    const int off = e - sg * 589824;
    float4 v;
    if (sg < 4)      v = *(const float4*)(a.x + e);
    else if (sg == 10 && off >= 767 * 768) v = make_float4(0.f, 0.f, 0.f, 0.f);
    else             v = *(const float4*)(srcW[sg - 4] + off);
    ushort4 o;
    o.x = f2bf(v.x); o.y = f2bf(v.y); o.z = f2bf(v.z); o.w = f2bf(v.w);
    *(ushort4*)(a.xb + e) = o;
}

// ---------------------------------------------------------------------------
// GEMM tile body. 64x128 tile, BK=64, 4 waves = 4 N-strips of 32. 24 KB smem.
// ---------------------------------------------------------------------------
template <bool OUT_F32>
__device__ void gemm_tile(const unsigned short* A, const unsigned short* W,
                          const float* bias, void* Cv, int z, int m0, int n0,
                          int tid, unsigned char* smem)
{
    unsigned short* As = (unsigned short*)smem;            //  8 KB
    unsigned short* Ws = (unsigned short*)(smem + 8192);   // 16 KB

    const int lane = tid & 63;
    const int wv_  = tid >> 6;
    const int quad = lane >> 4, l16 = lane & 15;

    floatx4 acc[4][2];
#pragma unroll
    for (int i = 0; i < 4; ++i)
#pragma unroll
        for (int j = 0; j < 2; ++j) acc[i][j] = (floatx4){0.f, 0.f, 0.f, 0.f};

    for (int k0 = 0; k0 < 768; k0 += 64) {
        __syncthreads();
#pragma unroll
        for (int r = 0; r < 2; ++r) {
            const int idx = tid + 256 * r;
            const int row = idx >> 3, cL = idx & 7, cD = cL ^ (row & 7);
            __builtin_amdgcn_global_load_lds(
                (__attribute__((address_space(1))) void*)(A + (size_t)(m0 + row) * 768 + k0 + cD * 8),
                (__attribute__((address_space(3))) void*)&As[idx * 8], 16, 0, 0);
        }
#pragma unroll
        for (int r = 0; r < 4; ++r) {
            const int idx = tid + 256 * r;
            const int row = idx >> 3, cL = idx & 7, cD = cL ^ (row & 7);
            __builtin_amdgcn_global_load_lds(
                (__attribute__((address_space(1))) void*)(W + (size_t)(n0 + row) * 768 + k0 + cD * 8),
                (__attribute__((address_space(3))) void*)&Ws[idx * 8], 16, 0, 0);
        }
        __syncthreads();

        bf16x8 av[4][2], bv[2][2];
#pragma unroll
        for (int mi = 0; mi < 4; ++mi)
#pragma unroll
            for (int kc = 0; kc < 2; ++kc)
                av[mi][kc] = lds8(As, mi * 16 + l16, kc * 4 + quad);
#pragma unroll
        for (int ni = 0; ni < 2; ++ni)
#pragma unroll
            for (int kc = 0; kc < 2; ++kc)
                bv[ni][kc] = lds8(Ws, wv_ * 32 + ni * 16 + l16, kc * 4 + quad);
#pragma unroll
        for (int mi = 0; mi < 4; ++mi)
#pragma unroll
            for (int ni = 0; ni < 2; ++ni)
#pragma unroll
                for (int kc = 0; kc < 2; ++kc)
                    acc[mi][ni] = __builtin_amdgcn_mfma_f32_16x16x32_bf16(
                        av[mi][kc], bv[ni][kc], acc[mi][ni], 0, 0, 0);
    }

#pragma unroll
    for (int ni = 0; ni < 2; ++ni) {
        const int n = n0 + wv_ * 32 + ni * 16 + l16;
        const float bn = bias[n];
#pragma unroll
        for (int mi = 0; mi < 4; ++mi) {
            const int mbase = m0 + mi * 16 + quad * 4;
            if (OUT_F32) {
                float* C = (float*)Cv;
#pragma unroll
                for (int reg = 0; reg < 4; ++reg)
                    C[(size_t)(mbase + reg) * 768 + n] = acc[mi][ni][reg] + bn;
            } else if (z == 2) {
                unsigned short* C = (unsigned short*)Cv;
                const int bb = mbase / S_, s = mbase - bb * S_;
                const int h = n >> 6, hd = n & 63;
                ushort4 o;
                o.x = f2bf(acc[mi][ni][0] + bn);
                o.y = f2bf(acc[mi][ni][1] + bn);
                o.z = f2bf(acc[mi][ni][2] + bn);
                o.w = f2bf(acc[mi][ni][3] + bn);
                *(ushort4*)&C[(((size_t)(bb * H_ + h) << 6) + hd) * S_ + s] = o;
            } else if (z < 2) {
                unsigned short* C = (unsigned short*)Cv;
#pragma unroll
                for (int reg = 0; reg < 4; ++reg) {
                    const int m = mbase + reg;
                    const int bb = m / S_, s = m - bb * S_;
                    const int h = n >> 6, hd = n & 63;
                    C[(((size_t)(bb * H_ + h) * S_ + s) << 6) + hd] =
                        f2bf(acc[mi][ni][reg] + bn);
                }
            } else {
                unsigned short* C = (unsigned short*)Cv;
#pragma unroll
                for (int reg = 0; reg < 4; ++reg)
                    C[(size_t)(mbase + reg) * 768 + n] = f2bf(acc[mi][ni][reg] + bn);
            }
        }
    }
}

__device__ __forceinline__ void proj_tile_dispatch(const KArgs& a, int t, int tid,
                                                   unsigned char* smem)
{
    int z, mt, nt;
    if (t < 864) { z = t / 288; const int r = t - z * 288; mt = r / 6; nt = r - mt * 6; }
    else { const int r2 = t - 864; z = 3 + r2 / 72; const int r = r2 % 72; mt = r / 6; nt = r - mt * 6; }
    const unsigned short* A = (z < 3) ? a.xb : a.relb;
    unsigned short* wbase = a.xb + 2359296;
    const unsigned short* W = wbase + (size_t)((z == 0) ? 0 : (z == 1) ? 1 : (z == 2) ? 2 : (z == 3) ? 4 : 5) * 589824;
    const float* bias = (z == 0) ? a.bq : (z == 1) ? a.bk : (z == 2) ? a.bv
                      : (z == 3) ? a.bpk : a.bpq;
    void* C = (z == 0) ? (void*)a.qb : (z == 1) ? (void*)a.kb : (z == 2) ? (void*)a.vtb
            : (z == 3) ? (void*)a.pkb : (void*)a.pqb;
    gemm_tile<false>(A, W, bias, C, z, mt * 64, nt * 128, tid, smem);
}

// ---------------------------------------------------------------------------
// Attention tile (R10/R12-proven body). Arena: Ks 8K|Vts 8K|PKs 16K|PQs 16K|
// CP 17K = 65 KB.
// ---------------------------------------------------------------------------
__device__ void attn_tile(const KArgs& a, int it, int h, int b, int jt,
                          int tid, unsigned char* smem)
{
    unsigned short* Ks  = (unsigned short*)smem;
    unsigned short* Vts = (unsigned short*)(smem + 8192);
    unsigned short* PKs = (unsigned short*)(smem + 16384);
    unsigned short* PQs = (unsigned short*)(smem + 32768);
    float* CP = (float*)(smem + 49152);

    const int lane = tid & 63, w = tid >> 6;
    const int l16  = lane & 15, quad = lane >> 4;
    const int ty = tid >> 4, tx = tid & 15;
    const int i0 = it * 64, j0 = jt * 64;
    const size_t bh = (size_t)(b * H_ + h);

    const unsigned short* kbase  = a.kb  + bh * S_ * 64;
    const unsigned short* vtbase = a.vtb + bh * 64 * S_;
    const int dbase = i0 - j0 + 320;

    bf16x8 qf[2];
#pragma unroll
    for (int ks = 0; ks < 2; ++ks)
        qf[ks] = gld8(a.qb + (bh * S_ + i0 + 16 * w + l16) * 64 + ks * 32 + quad * 8);

#pragma unroll
    for (int r = 0; r < 2; ++r) {
        const int idx = tid + 256 * r;
        const int row = idx >> 3, cL = idx & 7;
        const int cD = cL ^ (row & 7);
        __builtin_amdgcn_global_load_lds(
            (__attribute__((address_space(1))) void*)(kbase + (size_t)(j0 + row) * 64 + cD * 8),
            (__attribute__((address_space(3))) void*)&Ks[idx * 8], 16, 0, 0);
        __builtin_amdgcn_global_load_lds(
            (__attribute__((address_space(1))) void*)(vtbase + (size_t)row * S_ + j0 + cD * 8),
            (__attribute__((address_space(3))) void*)&Vts[idx * 8], 16, 0, 0);
    }
#pragma unroll
    for (int r = 0; r < 4; ++r) {
        const int idx = tid + 256 * r;
        const int row = idx >> 3, cL = idx & 7;
        const int cD = cL ^ (row & 7);
        const size_t go = (size_t)(dbase + row) * 768 + h * 64 + cD * 8;
        __builtin_amdgcn_global_load_lds(
            (__attribute__((address_space(1))) void*)(a.pkb + go),
            (__attribute__((address_space(3))) void*)&PKs[idx * 8], 16, 0, 0);
        __builtin_amdgcn_global_load_lds(
            (__attribute__((address_space(1))) void*)(a.pqb + go),
            (__attribute__((address_space(3))) void*)&PQs[idx * 8], 16, 0, 0);
    }

    float ai_r[4]; int si_r[4];
#pragma unroll
    for (int p = 0; p < 4; ++p) {
        const int ii = 4 * ty + p;
        ai_r[p] = fabsf(a.sep[b * S_ + i0 + ii]);
        si_r[p] = a.seg[b * S_ + i0 + ii];
    }

    const float sb  = a.same_bias[h];
    const float cb  = a.cross_bias[h];
    const float ssc = a.sep_scale[h];
    const float sd  = a.sep_decay[h];
    const float dec = fmaxf(sd, 0.f) + log1pf(__expf(-fabsf(sd))) + 1e-4f;
    const float isc = 0.07216878364870323f;

    __syncthreads();   // staging complete

    bf16x8 kf[4][2];
#pragma unroll
    for (int nj = 0; nj < 4; ++nj)
#pragma unroll
        for (int ks = 0; ks < 2; ++ks)
            kf[nj][ks] = lds8(Ks, 16 * nj + l16, ks * 4 + quad);

    // c2c
#pragma unroll
    for (int nj = 0; nj < 4; ++nj) {
        floatx4 acc = (floatx4){0.f, 0.f, 0.f, 0.f};
#pragma unroll
        for (int ks = 0; ks < 2; ++ks)
            acc = __builtin_amdgcn_mfma_f32_16x16x32_bf16(qf[ks], kf[nj][ks], acc, 0, 0, 0);
#pragma unroll
        for (int reg = 0; reg < 4; ++reg) {
            const int ii = 16 * w + quad * 4 + reg;
            CP[ii * 68 + 16 * nj + l16] = acc[reg];
        }
    }

    // c2p
#pragma unroll
    for (int f = 0; f < 5; ++f) {
        const int nd = w + f;
        floatx4 acc = (floatx4){0.f, 0.f, 0.f, 0.f};
#pragma unroll
        for (int ks = 0; ks < 2; ++ks) {
            bf16x8 bf = lds8(PKs, 16 * nd + l16, ks * 4 + quad);
            acc = __builtin_amdgcn_mfma_f32_16x16x32_bf16(qf[ks], bf, acc, 0, 0, 0);
        }
        const int ddloc = 16 * nd + l16;
#pragma unroll
        for (int reg = 0; reg < 4; ++reg) {
            const int ii = 16 * w + quad * 4 + reg;
            const int jj = ii - ddloc + 63;
            if (jj >= 0 && jj < 64)
                CP[ii * 68 + jj] += acc[reg];      // unique writer per cell
        }
    }

    // p2c
#pragma unroll
    for (int f = 0; f < 5; ++f) {
        const int nd = w + f;
        bf16x8 pqf[2];
#pragma unroll
        for (int ks = 0; ks < 2; ++ks)
            pqf[ks] = lds8(PQs, 16 * nd + l16, ks * 4 + quad);
#pragma unroll
        for (int g = 0; g < 2; ++g) {
            const int nj = (g == 0) ? (3 - f) : (4 - f);
            if (nj < 0 || nj > 3) continue;
            floatx4 acc = (floatx4){0.f, 0.f, 0.f, 0.f};
#pragma unroll
            for (int ks = 0; ks < 2; ++ks)
                acc = __builtin_amdgcn_mfma_f32_16x16x32_bf16(pqf[ks], kf[nj][ks], acc, 0, 0, 0);
            const int jj = 16 * nj + l16;
#pragma unroll
            for (int reg = 0; reg < 4; ++reg) {
                const int ddloc = 16 * nd + quad * 4 + reg;
                const int ii = ddloc + jj - 63;
                if (ii >= 16 * w && ii < 16 * w + 16)
                    CP[ii * 68 + jj] += acc[reg];  // unique writer per cell
            }
        }
    }

    // softmax
    unsigned short* Pp = (unsigned short*)CP;      // pitch 136 shorts
    float* pml = a.partml + (size_t)(jt * 576 + ((b * H_ + h) * 6 + it)) * 128;
#pragma unroll
    for (int p = 0; p < 4; ++p) {
        const int ii = 4 * ty + p;
        const float aii = ai_r[p];
        const int   sii = si_r[p];
        float lg[4];
        float tmax = -INFINITY;
#pragma unroll
        for (int r = 0; r < 4; ++r) {
            const int jl = 4 * tx + r;
            float xv = CP[ii * 68 + jl] * isc;
            const float ajv = fabsf(a.sep[b * S_ + j0 + jl]);
            const int   sjv = a.seg[b * S_ + j0 + jl];
            const float gap = fabsf(aii - ajv);
            const float bias = (sii == sjv) ? sb
                             : cb + __expf(-gap * dec) * ssc;
            xv += bias;
            if (a.mask[b * S_ + j0 + jl] == 0) xv = -9.0e15f;
            lg[r] = xv;
            tmax = fmaxf(tmax, xv);
        }
#pragma unroll
        for (int off = 1; off < 16; off <<= 1)
            tmax = fmaxf(tmax, __shfl_xor(tmax, off));
        float rs = 0.f;
        ushort4 pw;
#pragma unroll
        for (int r = 0; r < 4; ++r) {
            const float e = __expf(lg[r] - tmax);
            rs += e;
            ((unsigned short*)&pw)[r] = f2bf(e);
        }
#pragma unroll
        for (int off = 1; off < 16; off <<= 1)
            rs += __shfl_xor(rs, off);
        if (tx == 0) {
            pml[ii]      = tmax;
            pml[64 + ii] = rs;
        }
        *(ushort4*)&Pp[ii * 136 + 4 * tx] = pw;
    }

    // PV
    bf16x8 pA[2];
#pragma unroll
    for (int ks = 0; ks < 2; ++ks)
        pA[ks] = __builtin_bit_cast(bf16x8,
            *(const ux4*)&Pp[(16 * w + l16) * 136 + ks * 32 + quad * 8]);
    floatx4 O[4];
#pragma unroll
    for (int nd = 0; nd < 4; ++nd) {
        O[nd] = (floatx4){0.f, 0.f, 0.f, 0.f};
#pragma unroll
        for (int ks = 0; ks < 2; ++ks) {
            bf16x8 bf = lds8(Vts, 16 * nd + l16, ks * 4 + quad);
            O[nd] = __builtin_amdgcn_mfma_f32_16x16x32_bf16(pA[ks], bf, O[nd], 0, 0, 0);
        }
    }

    unsigned short* pO = a.partO + (size_t)(jt * 576 + ((b * H_ + h) * 6 + it)) * 4096;
#pragma unroll
    for (int nd = 0; nd < 4; ++nd) {
        const int d = 16 * nd + l16;
#pragma unroll
        for (int reg = 0; reg < 4; ++reg) {
            const int ii = 16 * w + quad * 4 + reg;
            pO[ii * 64 + d] = f2bf(O[nd][reg]);
        }
    }
}

// ---------------------------------------------------------------------------
// Merge tile (576 total).
// ---------------------------------------------------------------------------
__device__ void merge_tile(const KArgs& a, int idx, int tid)
{
    const int b  = idx / (H_ * 6);
    const int r  = idx - b * H_ * 6;
    const int h  = r / 6, it = r - h * 6;
    const int ii = tid >> 2, c = (tid & 3) * 16;

    float m[6], l[6];
#pragma unroll
    for (int jc = 0; jc < 6; ++jc) {
        const float* pml = a.partml + (size_t)(jc * 576 + idx) * 128;
        m[jc] = pml[ii];
        l[jc] = pml[64 + ii];
    }
    float M = m[0];
#pragma unroll
    for (int jc = 1; jc < 6; ++jc) M = fmaxf(M, m[jc]);
    float wsum = 0.f, wc[6];
#pragma unroll
    for (int jc = 0; jc < 6; ++jc) {
        wc[jc] = __expf(m[jc] - M);
        wsum += wc[jc] * l[jc];
    }
    const float inv = (wsum > 0.f) ? 1.f / wsum : 0.f;

    float o[16];
#pragma unroll
    for (int e = 0; e < 16; ++e) o[e] = 0.f;
#pragma unroll
    for (int jc = 0; jc < 6; ++jc) {
        const unsigned short* pO = a.partO + ((size_t)(jc * 576 + idx)) * 4096
                                 + ii * 64 + c;
        ux4 u0 = *(const ux4*)pO;
        ux4 u1 = *(const ux4*)(pO + 8);
        const unsigned short* us0 = (const unsigned short*)&u0;
        const unsigned short* us1 = (const unsigned short*)&u1;
#pragma unroll
        for (int e = 0; e < 8; ++e) {
            o[e]     += wc[jc] * bf2f(us0[e]);
            o[8 + e] += wc[jc] * bf2f(us1[e]);
        }
    }
    ushort4 w0, w1, w2, w3;
#pragma unroll
    for (int e = 0; e < 4; ++e) {
        ((unsigned short*)&w0)[e] = f2bf(o[e] * inv);
        ((unsigned short*)&w1)[e] = f2bf(o[4 + e] * inv);
        ((unsigned short*)&w2)[e] = f2bf(o[8 + e] * inv);
        ((unsigned short*)&w3)[e] = f2bf(o[12 + e] * inv);
    }
    unsigned short* dst = a.valsb + ((size_t)(b * S_ + it * 64 + ii)) * E_ + h * 64 + c;
    *(ushort4*)(dst)      = w0;
    *(ushort4*)(dst + 4)  = w1;
    *(ushort4*)(dst + 8)  = w2;
    *(ushort4*)(dst + 12) = w3;
}

// ---------------------------------------------------------------------------
// Fused cooperative kernel (grid-stride over nblk, occupancy-clamped).
// ---------------------------------------------------------------------------
__global__ __launch_bounds__(256) void fused_all(KArgs a)
{
    cg::grid_group grid = cg::this_grid();
    __shared__ __align__(16) unsigned char smem[66560];
    const int bid = blockIdx.x, tid = threadIdx.x;
    const int nblk = a.nblk;

    for (int i = bid * 256 + tid; i < 1622016; i += nblk * 256)
        convert_elem(a, i);
    grid.sync();

    for (int t = bid; t < 1008; t += nblk)
        proj_tile_dispatch(a, t, tid, smem);
    grid.sync();

    for (int t = bid; t < 3456; t += nblk) {
        __syncthreads();           // protect staging vs prev tile's readers
        const int it = t % 6;
        const int h  = (t / 6) % 12;
        const int zz = t / 72;
        const int b  = zz / 6, jt = zz - 6 * b;
        attn_tile(a, it, h, b, jt, tid, smem);
    }
    grid.sync();

    for (int t = bid; t < 576; t += nblk) merge_tile(a, t, tid);
    grid.sync();

    {
        unsigned short* wob = a.xb + 2359296 + (size_t)3 * 589824;
        for (int t = bid; t < 288; t += nblk) {
            const int mt = t / 6, nt = t - mt * 6;
            gemm_tile<true>(a.valsb, wob, a.bo, (void*)a.out, 0, mt * 64, nt * 128, tid, smem);
        }
    }
}

// ---------------------------------------------------------------------------
// Fallback standalone kernels (R12-equivalent pipeline).
// ---------------------------------------------------------------------------
__global__ __launch_bounds__(256) void k_convert(KArgs a)
{
    const int i = blockIdx.x * 256 + threadIdx.x;
    if (i < 1622016) convert_elem(a, i);
}
__global__ __launch_bounds__(256) void k_proj(KArgs a)
{
    __shared__ __align__(16) unsigned char smem[24576];
    proj_tile_dispatch(a, blockIdx.x, threadIdx.x, smem);
}
__global__ __launch_bounds__(256) void k_attn(KArgs a)
{
    __shared__ __align__(16) unsigned char smem[66560];
    const int b = blockIdx.z / 6, jt = blockIdx.z - 6 * b;
    attn_tile(a, blockIdx.x, blockIdx.y, b, jt, threadIdx.x, smem);
}
__global__ __launch_bounds__(256) void k_merge(KArgs a)
{
    merge_tile(a, blockIdx.x, threadIdx.x);
}
__global__ __launch_bounds__(256) void k_out(KArgs a)
{
    __shared__ __align__(16) unsigned char smem[24576];
    unsigned short* wob = a.xb + 2359296 + (size_t)3 * 589824;
    const int mt = blockIdx.x / 6, nt = blockIdx.x - mt * 6;
    gemm_tile<true>(a.valsb, wob, a.bo, (void*)a.out, 0, mt * 64, nt * 128,
                    threadIdx.x, smem);
}

// ---------------------------------------------------------------------------
// Launcher: occupancy-clamped cooperative launch; deterministic fallback to
// the 5-kernel pipeline if cooperative capacity is tiny or the launch fails.
// ---------------------------------------------------------------------------
extern "C" void kernel_launch(void* const* d_in, const int* in_sizes, int n_in,
                              void* d_out, int out_size, void* d_ws, size_t ws_size,
                              hipStream_t stream)
{
    const size_t QKVN = (size_t)B_ * S_ * E_;   // 2359296
    const size_t WN   = (size_t)768 * 768;      //  589824

    unsigned short* xb    = (unsigned short*)d_ws;
    unsigned short* relb  = xb + QKVN + 6 * WN;
    unsigned short* qb    = relb + WN;
    unsigned short* kb    = qb   + QKVN;
    unsigned short* vtb   = kb   + QKVN;
    unsigned short* pkb   = vtb  + QKVN;
    unsigned short* pqb   = pkb  + WN;
    unsigned short* valsb = pqb  + WN;
    unsigned short* partO = valsb + QKVN;
    float*          partml= (float*)(partO + (size_t)6 * 576 * 4096);

    KArgs a;
    a.x         = (const float*)d_in[0];
    a.mask      = (const int*)d_in[1];
    a.seg       = (const int*)d_in[2];
    a.sep       = (const float*)d_in[3];
    a.Wq        = (const float*)d_in[4];
    a.bq        = (const float*)d_in[5];
    a.Wk        = (const float*)d_in[6];
    a.bk        = (const float*)d_in[7];
    a.Wv        = (const float*)d_in[8];
    a.bv        = (const float*)d_in[9];
    a.rel128    = (const float*)d_in[10] + (size_t)128 * D_;
    a.Wpk       = (const float*)d_in[11];
    a.bpk       = (const float*)d_in[12];
    a.Wpq       = (const float*)d_in[13];
    a.bpq       = (const float*)d_in[14];
    a.same_bias = (const float*)d_in[15];
    a.cross_bias= (const float*)d_in[16];
    a.sep_scale = (const float*)d_in[17];
    a.sep_decay = (const float*)d_in[18];
    a.Wo        = (const float*)d_in[19];
    a.bo        = (const float*)d_in[20];
    a.xb = xb; a.relb = relb;
    a.qb = qb; a.kb = kb; a.vtb = vtb; a.pkb = pkb; a.pqb = pqb;
    a.valsb = valsb; a.partO = partO; a.partml = partml;
    a.out = (float*)d_out;
    a.nblk = 0;

    // ---- query real cooperative capacity for fused_all ----
    int dev = 0;
    (void)hipGetDevice(&dev);
    int cus = 0;
    (void)hipDeviceGetAttribute(&cus, hipDeviceAttributeMultiprocessorCount, dev);
    int occ = 0;
    (void)hipOccupancyMaxActiveBlocksPerMultiprocessor(&occ, fused_all, 256, 0);
    long cap = (long)occ * (long)cus;
    int nblk = (int)((cap > 512) ? 512 : cap);

    hipError_t err = hipErrorUnknown;
    if (nblk >= 64) {
        a.nblk = nblk;
        void* kp[] = { (void*)&a };
        err = hipLaunchCooperativeKernel((const void*)fused_all, dim3(nblk),
                                         dim3(256), kp, 0, stream);
    }
    if (err != hipSuccess) {
        // deterministic fallback: R12-equivalent 5-kernel pipeline
        k_convert<<<dim3(6336), 256, 0, stream>>>(a);
        k_proj   <<<dim3(1008), 256, 0, stream>>>(a);
        k_attn   <<<dim3(6, 12, 48), 256, 0, stream>>>(a);
        k_merge  <<<dim3(576), 256, 0, stream>>>(a);
        k_out    <<<dim3(288), 256, 0, stream>>>(a);
    }
}